// Round 13
// baseline (429.945 us; speedup 1.0000x reference)
//
#include <hip/hip_runtime.h>
#include <hip/hip_bf16.h>
#include <math.h>

#define NN   50000
#define NE   800000
#define HID  128
#define NRBF 32
#define NSCAN_BLOCKS ((NN + 255) / 256)   // 196

typedef __attribute__((ext_vector_type(8))) short short8;   // 8 bf16
typedef __attribute__((ext_vector_type(4))) float floatx4;  // MFMA acc

constexpr int TILE_N = 64;

__device__ __forceinline__ float silu_f(float x) {
  return x / (1.0f + __expf(-x));
}
__device__ __forceinline__ ushort f2bf(float f) {
  __hip_bfloat16 b = __float2bfloat16(f);
  return *reinterpret_cast<ushort*>(&b);
}
__device__ __forceinline__ float bf2f(ushort u) {
  union { uint u32; float f; } c; c.u32 = ((uint)u) << 16; return c.f;
}

// ---------- CSR build ----------
__global__ void counts_i_kernel(const int* __restrict__ edge_index, int* __restrict__ cnt) {
  const int e = blockIdx.x * blockDim.x + threadIdx.x;
  if (e < NE) atomicAdd(&cnt[edge_index[NE + e]], 1);
}

__global__ void scan_a_kernel(const int* __restrict__ cnt, int* __restrict__ incl,
                              int* __restrict__ bsum) {
  __shared__ int s[256];
  const int i = blockIdx.x * 256 + threadIdx.x;
  const int v = (i < NN) ? cnt[i] : 0;
  s[threadIdx.x] = v;
  __syncthreads();
  for (int off = 1; off < 256; off <<= 1) {
    const int x = (threadIdx.x >= off) ? s[threadIdx.x - off] : 0;
    __syncthreads();
    s[threadIdx.x] += x;
    __syncthreads();
  }
  if (i < NN) incl[i] = s[threadIdx.x];
  if (threadIdx.x == 255) bsum[blockIdx.x] = s[255];
}

__global__ void scan_b_kernel(int* __restrict__ bsum, int nb) {
  __shared__ int s[256];
  const int v = (threadIdx.x < nb) ? bsum[threadIdx.x] : 0;
  s[threadIdx.x] = v;
  __syncthreads();
  for (int off = 1; off < 256; off <<= 1) {
    const int x = (threadIdx.x >= off) ? s[threadIdx.x - off] : 0;
    __syncthreads();
    s[threadIdx.x] += x;
    __syncthreads();
  }
  bsum[threadIdx.x] = s[threadIdx.x] - v;   // exclusive
}

__global__ void scan_c_kernel(int* __restrict__ incl, const int* __restrict__ cnt,
                              const int* __restrict__ bsumex, float* __restrict__ cf) {
  const int i = blockIdx.x * 256 + threadIdx.x;
  if (i < NN) {
    const int c = cnt[i];
    incl[i] = incl[i] - c + bsumex[blockIdx.x];  // exclusive start
    cf[i] = (float)c;
  }
}

__global__ void perm_kernel(const int* __restrict__ edge_index, const int* __restrict__ edge_type,
                            const int* __restrict__ starts,
                            int* __restrict__ cursor, int2* __restrict__ rec) {
  const int e = blockIdx.x * blockDim.x + threadIdx.x;
  if (e < NE) {
    const int s  = edge_index[e];
    const int d  = edge_index[NE + e];
    const int et = edge_type[e];
    const int pos = atomicAdd(&cursor[d], 1);
    rec[starts[d] + pos] = make_int2(s | (et << 24), d);
  }
}

// ---------- weight prep ----------
// h [NN,HID] f32 -> bf16 (R2-proven pattern)
__global__ void convert_h_kernel(const float* __restrict__ h, ushort* __restrict__ hb) {
  const int tid = blockIdx.x * blockDim.x + threadIdx.x;
  if (tid >= NN * HID / 8) return;
  const float4 f0 = reinterpret_cast<const float4*>(h)[tid * 2];
  const float4 f1 = reinterpret_cast<const float4*>(h)[tid * 2 + 1];
  union { ushort u[8]; uint4 v; } o;
  o.u[0] = f2bf(f0.x); o.u[1] = f2bf(f0.y); o.u[2] = f2bf(f0.z); o.u[3] = f2bf(f0.w);
  o.u[4] = f2bf(f1.x); o.u[5] = f2bf(f1.y); o.u[6] = f2bf(f1.z); o.u[7] = f2bf(f1.w);
  reinterpret_cast<uint4*>(hb)[tid] = o.v;
}

// embp[2][128] = emb @ mw1[256:384] + mb1   (f32, bias folded)
__global__ void embp_kernel(const float* __restrict__ emb, const float* __restrict__ mw1,
                            const float* __restrict__ mb1, float* __restrict__ embp) {
  const int t = threadIdx.x;
  const int row = t >> 7, col = t & 127;
  float s = mb1[col];
  #pragma unroll 4
  for (int k = 0; k < HID; ++k)
    s = fmaf(emb[row * HID + k], mw1[(256 + k) * HID + col], s);
  embp[row * HID + col] = s;
}

// w1x [64 x 128]: rows 0..31 = mw1[384:416] (rbf), row 32 = mw1[416] (dist),
// rows 33,34 = embp (edge-type one-hot), rest 0.
__global__ void build_w1x_kernel(const float* __restrict__ mw1, const float* __restrict__ embp,
                                 float* __restrict__ w1x) {
  const int tid = blockIdx.x * 256 + threadIdx.x;
  if (tid >= 64 * 128) return;
  const int r = tid >> 7, c = tid & 127;
  float v = 0.0f;
  if (r < 32)       v = mw1[(384 + r) * HID + c];
  else if (r == 32) v = mw1[416 * HID + c];
  else if (r == 33) v = embp[c];
  else if (r == 34) v = embp[HID + c];
  w1x[tid] = v;
}

// Pack W [Korig x 128] f32 into bf16 MFMA B-fragment order:
// out[((kk*8 + c)*64 + lane)*8 + j] = W[kk*32 + (lane>>4)*8 + j][c*16 + (lane&15)]
__global__ void pack_w_kernel(const float* __restrict__ W, ushort* __restrict__ out,
                              int Korig, int nks) {
  const int tid = blockIdx.x * blockDim.x + threadIdx.x;
  if (tid >= nks * 8 * 64) return;
  const int l = tid & 63;
  const int c = (tid >> 6) & 7;
  const int kk = tid >> 9;
  union { ushort u[8]; uint4 v; } o;
  #pragma unroll
  for (int j = 0; j < 8; ++j) {
    const int k = kk * 32 + ((l >> 4) * 8) + j;
    const float f = (k < Korig) ? W[k * HID + c * 16 + (l & 15)] : 0.0f;
    o.u[j] = f2bf(f);
  }
  reinterpret_cast<uint4*>(out)[tid] = o.v;
}

// 64 CSR-ordered edges/block. Layer 1 entirely on MFMA:
//   acc = hb[src]@wap (staged A1) + hb[dst]@wbp (staged A2, same LDS window)
//       + [rbf | dist,onehot]@w1xp (K=64).
// LDS: sBuf[0..16K) = A1/A2/X/MSG bf16 (unioned, 256B swizzled rows);
// sRbf 4KB. launch_bounds(256,4): 128-VGPR budget (R8 lesson: never cap below
// the accumulators — (256,7) forced 36 VGPRs + 722 MB scratch spill).
__global__ __launch_bounds__(256, 4)
void edge_kernel(const ushort* __restrict__ hb,
                 const float* __restrict__ pos, const int2* __restrict__ rec,
                 const ushort* __restrict__ wap, const ushort* __restrict__ wbp,
                 const ushort* __restrict__ w1xp, const ushort* __restrict__ w2p,
                 const float* __restrict__ mb2,
                 float* sums)
{
  __shared__ __align__(16) char  sBuf[16384];
  __shared__ __align__(16) uint4 sRbf[256];   // 4 KB
  __shared__ int   sDst[64];
  __shared__ int   sEt[64];
  __shared__ float sDistF[64];

  const int t  = threadIdx.x;
  const int e0 = blockIdx.x * 64;
  const int e  = t >> 2, q = t & 3;

  // phase0: edge record (coalesced, 4-lane redundant) + dist + rbf
  const int2 rc = rec[e0 + e];
  const int src = rc.x & 0x00FFFFFF;
  const int et  = ((unsigned)rc.x) >> 24;
  const int dst = rc.y;

  const float dx = pos[3*src]   - pos[3*dst];
  const float dy = pos[3*src+1] - pos[3*dst+1];
  const float dz = pos[3*src+2] - pos[3*dst+2];
  const float dist = sqrtf(dx*dx + dy*dy + dz*dz);
  if (q == 0) { sDst[e] = dst; sEt[e] = et; sDistF[e] = dist; }

  const int sm = (e & 7) << 4;

  // stage A1 = hb[src] (proj-proven pattern: pure uint4 copies)
  {
    const ushort* const hr = hb + (long)src * HID;
    #pragma unroll
    for (int m = 0; m < 4; ++m) {
      const int c = q * 32 + m * 8;
      const uint4 v = *reinterpret_cast<const uint4*>(hr + c);
      *reinterpret_cast<uint4*>(sBuf + ((e * 256 + c * 2) ^ sm)) = v;
    }
    const float step  = 6.0f / 31.0f;
    const float gamma = 1.0f / (step * step);
    const int r0 = q * 8;
    union { ushort u[8]; uint4 v; } o;
    #pragma unroll
    for (int j = 0; j < 8; ++j) {
      const float dd = dist - step * (float)(r0 + j);
      o.u[j] = f2bf(__expf(-gamma * dd * dd));
    }
    sRbf[e * 4 + (q ^ (e & 3))] = o.v;
  }
  __syncthreads();   // (1) A1 + rbf + sDst/sEt/sDistF visible

  const int lane = t & 63;
  const int w    = t >> 6;
  const int rt0  = (w & 1) * 2;
  const int ct0  = (w >> 1) * 4;
  const int lrow = lane & 15;
  const int lk16 = (lane >> 4) * 16;
  const int rowA0 = rt0 * 16 + lrow, rowA1 = rowA0 + 16;
  const int smA0 = (rowA0 & 7) << 4, smA1 = (rowA1 & 7) << 4;

  floatx4 acc[2][4] = {};

  // acc += A1 @ wap  (h_src projection)
  {
    const ushort* const bbase = wap + ((size_t)ct0 * 64 + lane) * 8;
    #pragma unroll
    for (int kk = 0; kk < 4; ++kk) {
      short8 afr[2];
      afr[0] = *reinterpret_cast<const short8*>(sBuf + rowA0 * 256 + ((kk*64 + lk16) ^ smA0));
      afr[1] = *reinterpret_cast<const short8*>(sBuf + rowA1 * 256 + ((kk*64 + lk16) ^ smA1));
      #pragma unroll
      for (int j = 0; j < 4; ++j) {
        const short8 b = *reinterpret_cast<const short8*>(bbase + kk * 4096 + j * 512);
        acc[0][j] = __builtin_amdgcn_mfma_f32_16x16x32_bf16(afr[0], b, acc[0][j], 0, 0, 0);
        acc[1][j] = __builtin_amdgcn_mfma_f32_16x16x32_bf16(afr[1], b, acc[1][j], 0, 0, 0);
      }
    }
  }
  __syncthreads();   // (2) all A1 frag reads done; sBuf reusable

  // stage A2 = hb[dst]
  {
    const ushort* const hr = hb + (long)dst * HID;
    #pragma unroll
    for (int m = 0; m < 4; ++m) {
      const int c = q * 32 + m * 8;
      const uint4 v = *reinterpret_cast<const uint4*>(hr + c);
      *reinterpret_cast<uint4*>(sBuf + ((e * 256 + c * 2) ^ sm)) = v;
    }
  }
  __syncthreads();   // (3) A2 visible

  // acc += A2 @ wbp  (h_dst projection)
  {
    const ushort* const bbase = wbp + ((size_t)ct0 * 64 + lane) * 8;
    #pragma unroll
    for (int kk = 0; kk < 4; ++kk) {
      short8 afr[2];
      afr[0] = *reinterpret_cast<const short8*>(sBuf + rowA0 * 256 + ((kk*64 + lk16) ^ smA0));
      afr[1] = *reinterpret_cast<const short8*>(sBuf + rowA1 * 256 + ((kk*64 + lk16) ^ smA1));
      #pragma unroll
      for (int j = 0; j < 4; ++j) {
        const short8 b = *reinterpret_cast<const short8*>(bbase + kk * 4096 + j * 512);
        acc[0][j] = __builtin_amdgcn_mfma_f32_16x16x32_bf16(afr[0], b, acc[0][j], 0, 0, 0);
        acc[1][j] = __builtin_amdgcn_mfma_f32_16x16x32_bf16(afr[1], b, acc[1][j], 0, 0, 0);
      }
    }
  }
  // acc += [rbf | dist,onehot] @ w1xp (K=64; reads sRbf + registers only)
  {
    const short8 a0 = *reinterpret_cast<const short8*>(&sRbf[rowA0 * 4 + ((lane >> 4) ^ (rowA0 & 3))]);
    const short8 a1 = *reinterpret_cast<const short8*>(&sRbf[rowA1 * 4 + ((lane >> 4) ^ (rowA1 & 3))]);
    const ushort* const bb = w1xp + ((size_t)ct0 * 64 + lane) * 8;
    #pragma unroll
    for (int j = 0; j < 4; ++j) {
      const short8 b = *reinterpret_cast<const short8*>(bb + j * 512);
      acc[0][j] = __builtin_amdgcn_mfma_f32_16x16x32_bf16(a0, b, acc[0][j], 0, 0, 0);
      acc[1][j] = __builtin_amdgcn_mfma_f32_16x16x32_bf16(a1, b, acc[1][j], 0, 0, 0);
    }
    short8 x0 = {0,0,0,0,0,0,0,0}, x1 = {0,0,0,0,0,0,0,0};
    if ((lane >> 4) == 0) {   // k = 32..39 slots: [dist, et==0, et==1, 0...]
      x0[0] = (short)f2bf(sDistF[rowA0]);
      x0[1] = (sEt[rowA0] == 0) ? (short)0x3F80 : (short)0;
      x0[2] = (sEt[rowA0] == 1) ? (short)0x3F80 : (short)0;
      x1[0] = (short)f2bf(sDistF[rowA1]);
      x1[1] = (sEt[rowA1] == 0) ? (short)0x3F80 : (short)0;
      x1[2] = (sEt[rowA1] == 1) ? (short)0x3F80 : (short)0;
    }
    #pragma unroll
    for (int j = 0; j < 4; ++j) {
      const short8 b = *reinterpret_cast<const short8*>(bb + 4096 + j * 512);
      acc[0][j] = __builtin_amdgcn_mfma_f32_16x16x32_bf16(x0, b, acc[0][j], 0, 0, 0);
      acc[1][j] = __builtin_amdgcn_mfma_f32_16x16x32_bf16(x1, b, acc[1][j], 0, 0, 0);
    }
  }
  __syncthreads();   // (4) all A2 frag reads done; sBuf reusable for X

  // silu -> X (bf16)
  #pragma unroll
  for (int i = 0; i < 2; ++i)
    #pragma unroll
    for (int r = 0; r < 4; ++r) {
      const int row = (rt0 + i) * 16 + (lane >> 4) * 4 + r;
      const int smr = (row & 7) << 4;
      #pragma unroll
      for (int j = 0; j < 4; ++j) {
        const int col = (ct0 + j) * 16 + lrow;
        *reinterpret_cast<ushort*>(sBuf + row * 256 + ((col * 2) ^ smr)) =
            f2bf(silu_f(acc[i][j][r]));
      }
    }
  __syncthreads();   // (5) X visible

  // layer 2: [64 x 128] @ [128 x 128]
  floatx4 acc2[2][4] = {};
  {
    const ushort* const bbase = w2p + ((size_t)ct0 * 64 + lane) * 8;
    #pragma unroll 2
    for (int kk = 0; kk < 4; ++kk) {
      short8 bfr[4];
      #pragma unroll
      for (int j = 0; j < 4; ++j)
        bfr[j] = *reinterpret_cast<const short8*>(bbase + kk * 4096 + j * 512);
      short8 afr[2];
      afr[0] = *reinterpret_cast<const short8*>(sBuf + rowA0 * 256 + ((kk*64 + lk16) ^ smA0));
      afr[1] = *reinterpret_cast<const short8*>(sBuf + rowA1 * 256 + ((kk*64 + lk16) ^ smA1));
      #pragma unroll
      for (int i = 0; i < 2; ++i)
        #pragma unroll
        for (int j = 0; j < 4; ++j)
          acc2[i][j] = __builtin_amdgcn_mfma_f32_16x16x32_bf16(afr[i], bfr[j], acc2[i][j], 0, 0, 0);
    }
  }
  __syncthreads();   // (6) all X reads done; sBuf reusable for MSG

  // epilogue: bias + silu -> MSG (bf16)
  {
    float b2v[4];
    #pragma unroll
    for (int j = 0; j < 4; ++j) b2v[j] = mb2[(ct0 + j) * 16 + lrow];
    #pragma unroll
    for (int i = 0; i < 2; ++i)
      #pragma unroll
      for (int r = 0; r < 4; ++r) {
        const int row = (rt0 + i) * 16 + (lane >> 4) * 4 + r;
        const int smr = (row & 7) << 4;
        #pragma unroll
        for (int j = 0; j < 4; ++j) {
          const int col = (ct0 + j) * 16 + lrow;
          *reinterpret_cast<ushort*>(sBuf + row * 256 + ((col * 2) ^ smr)) =
              f2bf(silu_f(acc2[i][j][r] + b2v[j]));
        }
      }
  }
  __syncthreads();   // (7) MSG visible

  // dst-segment reduction: one atomicAdd per (segment, column)
  {
    const int half = t >> 7;
    const int c    = t & 127;
    const int r0   = half * 32;
    int cur = sDst[r0];
    float accv = 0.0f;
    for (int r = r0; r < r0 + 32; ++r) {
      const int d = sDst[r];
      const float mv = bf2f(*reinterpret_cast<const ushort*>(
          sBuf + r * 256 + ((c * 2) ^ ((r & 7) << 4))));
      if (d != cur) {
        atomicAdd(&sums[(long)cur * HID + c], accv);
        accv = 0.0f;
        cur = d;
      }
      accv += mv;
    }
    atomicAdd(&sums[(long)cur * HID + c], accv);
  }
}

// f32-VALU node kernel with bf16 LDS staging (R12-proven).
// sums aliases out (d_out) — no __restrict__ on either.
__global__ __launch_bounds__(256, 4)
void node_kernel(const float* __restrict__ h,
                 const float* sums, const float* __restrict__ counts,
                 const int* __restrict__ node_type,
                 const float* __restrict__ uw1, const float* __restrict__ ub1,
                 const float* __restrict__ uw2, const float* __restrict__ ub2,
                 const float* __restrict__ ln_g, const float* __restrict__ ln_b,
                 float* out)
{
  __shared__ ushort sIn[TILE_N * 256];   // 32 KB bf16

  const int t  = threadIdx.x;
  const int n0 = blockIdx.x * TILE_N;

  for (int idx = t; idx < TILE_N*HID; idx += 256) {
    const int n = idx >> 7, c = idx & (HID-1);
    const int node = n0 + n;
    float hv = 0.f, av = 0.f;
    if (node < NN) {
      hv = h[(long)node*HID + c];
      av = sums[(long)node*HID + c] / fmaxf(counts[node], 1.0f);
    }
    sIn[n*256 + c]       = f2bf(hv);
    sIn[n*256 + HID + c] = f2bf(av);
  }
  __syncthreads();   // (B0)

  const int tx = t & 31;
  const int ty = t >> 5;

  // GEMM1: [64 x 256] @ [256 x 128], f32 FMA with bf16 A
  const float* wp = uw1 + tx*4;
  float4 acc[8];
  #pragma unroll
  for (int i = 0; i < 8; ++i) acc[i] = make_float4(0.f,0.f,0.f,0.f);
  for (int k = 0; k < 2*HID; ++k) {
    const float4 w = *reinterpret_cast<const float4*>(wp + (long)k*HID);
    #pragma unroll
    for (int i = 0; i < 8; ++i) {
      const float a = bf2f(sIn[(ty*8+i)*256 + k]);
      acc[i].x = fmaf(a, w.x, acc[i].x);
      acc[i].y = fmaf(a, w.y, acc[i].y);
      acc[i].z = fmaf(a, w.z, acc[i].z);
      acc[i].w = fmaf(a, w.w, acc[i].w);
    }
  }
  __syncthreads();   // (B1)

  const float4 b1 = *reinterpret_cast<const float4*>(ub1 + tx*4);
  #pragma unroll
  for (int i = 0; i < 8; ++i) {
    const int e = ty*8 + i;
    float4 v = acc[i];
    ushort4 s;
    s.x = f2bf(silu_f(v.x + b1.x)); s.y = f2bf(silu_f(v.y + b1.y));
    s.z = f2bf(silu_f(v.z + b1.z)); s.w = f2bf(silu_f(v.w + b1.w));
    *reinterpret_cast<ushort4*>(&sIn[e*256 + tx*4]) = s;   // sU in h-half
  }
  __syncthreads();   // (B2)

  // GEMM2: [64 x 128] @ [128 x 128]
  const float* wp2 = uw2 + tx*4;
  float4 acc2[8];
  #pragma unroll
  for (int i = 0; i < 8; ++i) acc2[i] = make_float4(0.f,0.f,0.f,0.f);
  for (int k = 0; k < HID; ++k) {
    const float4 w = *reinterpret_cast<const float4*>(wp2 + (long)k*HID);
    #pragma unroll
    for (int i = 0; i < 8; ++i) {
      const float a = bf2f(sIn[(ty*8+i)*256 + k]);
      acc2[i].x = fmaf(a, w.x, acc2[i].x);
      acc2[i].y = fmaf(a, w.y, acc2[i].y);
      acc2[i].z = fmaf(a, w.z, acc2[i].z);
      acc2[i].w = fmaf(a, w.w, acc2[i].w);
    }
  }
  const float4 b2 = *reinterpret_cast<const float4*>(ub2 + tx*4);
  #pragma unroll
  for (int i = 0; i < 8; ++i) {
    const int e = ty*8 + i;
    ushort4 s;
    s.x = f2bf(acc2[i].x + b2.x); s.y = f2bf(acc2[i].y + b2.y);
    s.z = f2bf(acc2[i].z + b2.z); s.w = f2bf(acc2[i].w + b2.w);
    *reinterpret_cast<ushort4*>(&sIn[e*256 + HID + tx*4]) = s;   // u in agg-half
  }
  __syncthreads();   // (B3)

  {  // LayerNorm + residual + mask; x = h(f32) + u(bf16)
    const int n = t >> 2, q = t & 3;
    const int node = n0 + n;
    if (node < NN) {
      float4 hv4[8], xv4[8];
      float smm = 0.f, sqq = 0.f;
      #pragma unroll
      for (int m = 0; m < 8; ++m) {
        const int c = q * 32 + m * 4;
        const ushort4 us = *reinterpret_cast<const ushort4*>(&sIn[n*256 + HID + c]);
        const float4 hv = *reinterpret_cast<const float4*>(h + (long)node * HID + c);
        float4 x;
        x.x = hv.x + bf2f(us.x); x.y = hv.y + bf2f(us.y);
        x.z = hv.z + bf2f(us.z); x.w = hv.w + bf2f(us.w);
        hv4[m] = hv; xv4[m] = x;
        smm += x.x + x.y + x.z + x.w;
        sqq += x.x*x.x + x.y*x.y + x.z*x.z + x.w*x.w;
      }
      smm += __shfl_xor(smm, 1); sqq += __shfl_xor(sqq, 1);
      smm += __shfl_xor(smm, 2); sqq += __shfl_xor(sqq, 2);
      const float mu = smm * (1.0f / HID);
      float var = sqq * (1.0f / HID) - mu * mu;
      var = fmaxf(var, 0.0f);
      const float rs = rsqrtf(var + 1e-5f);
      const bool lig = (node_type[node] == 0);
      #pragma unroll
      for (int m = 0; m < 8; ++m) {
        const int c = q * 32 + m * 4;
        const float4 g = *reinterpret_cast<const float4*>(ln_g + c);
        const float4 b = *reinterpret_cast<const float4*>(ln_b + c);
        float4 o;
        o.x = lig ? (xv4[m].x - mu) * rs * g.x + b.x : hv4[m].x;
        o.y = lig ? (xv4[m].y - mu) * rs * g.y + b.y : hv4[m].y;
        o.z = lig ? (xv4[m].z - mu) * rs * g.z + b.z : hv4[m].z;
        o.w = lig ? (xv4[m].w - mu) * rs * g.w + b.w : hv4[m].w;
        *reinterpret_cast<float4*>(out + (long)node * HID + c) = o;
      }
    }
  }
}

extern "C" void kernel_launch(void* const* d_in, const int* in_sizes, int n_in,
                              void* d_out, int out_size, void* d_ws, size_t ws_size,
                              hipStream_t stream)
{
  const float* h    = (const float*)d_in[0];
  const float* pos  = (const float*)d_in[1];
  const int*   eidx = (const int*)  d_in[2];
  const int*   etyp = (const int*)  d_in[3];
  const int*   ntyp = (const int*)  d_in[4];
  const float* emb  = (const float*)d_in[5];
  const float* mw1  = (const float*)d_in[6];
  const float* mb1  = (const float*)d_in[7];
  const float* mw2  = (const float*)d_in[8];
  const float* mb2  = (const float*)d_in[9];
  const float* uw1  = (const float*)d_in[10];
  const float* ub1  = (const float*)d_in[11];
  const float* uw2  = (const float*)d_in[12];
  const float* ub2  = (const float*)d_in[13];
  const float* lng  = (const float*)d_in[14];
  const float* lnb  = (const float*)d_in[15];

  // f32 sums accumulate in d_out (exactly NN*HID f32); node_kernel reads a
  // node's sums strictly before writing the same node's output row.
  float* sums = (float*)d_out;

  // workspace layout (~22 MB)
  float*  counts_f = (float*)d_ws;                      // NN f32
  ushort* hb       = (ushort*)(counts_f + NN);          // NN*HID bf16
  float*  embp     = (float*)(hb + (long)NN*HID);       // 256 f32
  float*  w1x      = embp + 256;                        // 64*128 f32
  ushort* wap      = (ushort*)(w1x + 64*128);           // 4 ks
  ushort* wbp      = wap  + 4*4096;                     // 4 ks
  ushort* w1xp     = wbp  + 4*4096;                     // 2 ks
  ushort* w2p      = w1xp + 2*4096;                     // 4 ks
  int*    cnt_i    = (int*)(w2p + 4*4096);              // NN
  int*    cursor   = cnt_i + NN;                        // NN (adjacent: one memset)
  int*    starts   = cursor + NN;                       // NN
  int*    bsum     = starts + NN;                       // 256
  int2*   rec      = (int2*)(bsum + 256);               // NE * 8B

  hipMemsetAsync(sums, 0, (size_t)NN*HID*4, stream);
  hipMemsetAsync(cnt_i, 0, (size_t)NN*2*4, stream);     // cnt_i + cursor

  // CSR build
  counts_i_kernel<<<(NE + 255)/256, 256, 0, stream>>>(eidx, cnt_i);
  scan_a_kernel<<<NSCAN_BLOCKS, 256, 0, stream>>>(cnt_i, starts, bsum);
  scan_b_kernel<<<1, 256, 0, stream>>>(bsum, NSCAN_BLOCKS);
  scan_c_kernel<<<NSCAN_BLOCKS, 256, 0, stream>>>(starts, cnt_i, bsum, counts_f);
  perm_kernel<<<(NE + 255)/256, 256, 0, stream>>>(eidx, etyp, starts, cursor, rec);

  // weight prep
  convert_h_kernel<<<(NN*HID/8 + 255)/256, 256, 0, stream>>>(h, hb);
  embp_kernel<<<1, 256, 0, stream>>>(emb, mw1, mb1, embp);
  build_w1x_kernel<<<32, 256, 0, stream>>>(mw1, embp, w1x);
  pack_w_kernel<<<8, 256, 0, stream>>>(mw1,           wap,  128, 4);
  pack_w_kernel<<<8, 256, 0, stream>>>(mw1 + 128*HID, wbp,  128, 4);
  pack_w_kernel<<<4, 256, 0, stream>>>(w1x,           w1xp,  64, 2);
  pack_w_kernel<<<8, 256, 0, stream>>>(mw2,           w2p,  128, 4);

  edge_kernel<<<NE/64, 256, 0, stream>>>(hb, pos, rec, wap, wbp,
                                         w1xp, w2p, mb2, sums);
  node_kernel<<<(NN + 63)/64, 256, 0, stream>>>(h, sums, counts_f, ntyp,
                                                uw1, ub1, uw2, ub2,
                                                lng, lnb, (float*)d_out);
}

// Round 14
// 406.129 us; speedup vs baseline: 1.0586x; 1.0586x over previous
//
#include <hip/hip_runtime.h>
#include <hip/hip_bf16.h>
#include <math.h>

#define NN   50000
#define NE   800000
#define HID  128
#define NRBF 32
#define NSCAN_BLOCKS ((NN + 255) / 256)   // 196

typedef __attribute__((ext_vector_type(8))) short short8;   // 8 bf16
typedef __attribute__((ext_vector_type(4))) float floatx4;  // MFMA acc

constexpr int TILE_N = 64;

__device__ __forceinline__ float silu_f(float x) {
  return x / (1.0f + __expf(-x));
}
__device__ __forceinline__ ushort f2bf(float f) {
  __hip_bfloat16 b = __float2bfloat16(f);
  return *reinterpret_cast<ushort*>(&b);
}
__device__ __forceinline__ float bf2f(ushort u) {
  union { uint u32; float f; } c; c.u32 = ((uint)u) << 16; return c.f;
}

// ---------- CSR build ----------
__global__ void counts_i_kernel(const int* __restrict__ edge_index, int* __restrict__ cnt) {
  const int e = blockIdx.x * blockDim.x + threadIdx.x;
  if (e < NE) atomicAdd(&cnt[edge_index[NE + e]], 1);
}

__global__ void scan_a_kernel(const int* __restrict__ cnt, int* __restrict__ incl,
                              int* __restrict__ bsum) {
  __shared__ int s[256];
  const int i = blockIdx.x * 256 + threadIdx.x;
  const int v = (i < NN) ? cnt[i] : 0;
  s[threadIdx.x] = v;
  __syncthreads();
  for (int off = 1; off < 256; off <<= 1) {
    const int x = (threadIdx.x >= off) ? s[threadIdx.x - off] : 0;
    __syncthreads();
    s[threadIdx.x] += x;
    __syncthreads();
  }
  if (i < NN) incl[i] = s[threadIdx.x];
  if (threadIdx.x == 255) bsum[blockIdx.x] = s[255];
}

__global__ void scan_b_kernel(int* __restrict__ bsum, int nb) {
  __shared__ int s[256];
  const int v = (threadIdx.x < nb) ? bsum[threadIdx.x] : 0;
  s[threadIdx.x] = v;
  __syncthreads();
  for (int off = 1; off < 256; off <<= 1) {
    const int x = (threadIdx.x >= off) ? s[threadIdx.x - off] : 0;
    __syncthreads();
    s[threadIdx.x] += x;
    __syncthreads();
  }
  bsum[threadIdx.x] = s[threadIdx.x] - v;   // exclusive
}

// incl -> starts (in place) + reciprocal float counts (node multiplies, not divides)
__global__ void scan_c_kernel(int* __restrict__ incl, const int* __restrict__ cnt,
                              const int* __restrict__ bsumex, float* __restrict__ cf) {
  const int i = blockIdx.x * 256 + threadIdx.x;
  if (i < NN) {
    const int c = cnt[i];
    incl[i] = incl[i] - c + bsumex[blockIdx.x];  // exclusive start
    cf[i] = 1.0f / (float)max(c, 1);
  }
}

__global__ void perm_kernel(const int* __restrict__ edge_index, const int* __restrict__ edge_type,
                            const int* __restrict__ starts,
                            int* __restrict__ cursor, int2* __restrict__ rec) {
  const int e = blockIdx.x * blockDim.x + threadIdx.x;
  if (e < NE) {
    const int s  = edge_index[e];
    const int d  = edge_index[NE + e];
    const int et = edge_type[e];
    const int pos = atomicAdd(&cursor[d], 1);
    rec[starts[d] + pos] = make_int2(s | (et << 24), d);
  }
}

// ---------- weight prep ----------
// Fused: embp[2][128] = emb @ mw1[256:384] + mb1, and w1x [64 x 128]
// (rows 0..31 = mw1[384:416], row 32 = mw1[416], rows 33/34 = embp, rest 0).
__global__ void prep_kernel(const float* __restrict__ emb, const float* __restrict__ mw1,
                            const float* __restrict__ mb1,
                            float* __restrict__ embp, float* __restrict__ w1x) {
  const int t = threadIdx.x;
  const int row = t >> 7, col = t & 127;
  float s = mb1[col];
  #pragma unroll 4
  for (int k = 0; k < HID; ++k)
    s = fmaf(emb[row * HID + k], mw1[(256 + k) * HID + col], s);
  embp[row * HID + col] = s;
  w1x[(33 + row) * HID + col] = s;
  // rows 0..32 and 35..63 (independent of embp)
  for (int i = t; i < 64 * 128; i += 256) {
    const int r = i >> 7, c = i & 127;
    if (r < 32)       w1x[i] = mw1[(384 + r) * HID + c];
    else if (r == 32) w1x[i] = mw1[416 * HID + c];
    else if (r >= 35) w1x[i] = 0.0f;
  }
}

// Fused pack of all four B matrices (byte-identical inner body to the proven
// pack_w_kernel; blockIdx-range dispatch). Layout (contiguous 4096-elem ksteps):
// [wap(4ks) | wbp(4) | w1xp(2) | w2p(4)] -> blocks [0,8)|[8,16)|[16,20)|[20,28)
__global__ void pack4_kernel(const float* __restrict__ mw1, const float* __restrict__ w1x,
                             const float* __restrict__ mw2, ushort* __restrict__ outb) {
  const int bid = blockIdx.x;
  const float* W; int Korig, nks, base_ks, bloc;
  if (bid < 8)       { W = mw1;            Korig = 128; nks = 4; base_ks = 0;  bloc = bid; }
  else if (bid < 16) { W = mw1 + 128*HID;  Korig = 128; nks = 4; base_ks = 4;  bloc = bid - 8; }
  else if (bid < 20) { W = w1x;            Korig = 64;  nks = 2; base_ks = 8;  bloc = bid - 16; }
  else               { W = mw2;            Korig = 128; nks = 4; base_ks = 10; bloc = bid - 20; }
  const int tid = bloc * 256 + threadIdx.x;
  if (tid >= nks * 8 * 64) return;
  const int l = tid & 63;
  const int c = (tid >> 6) & 7;
  const int kk = tid >> 9;
  union { ushort u[8]; uint4 v; } o;
  #pragma unroll
  for (int j = 0; j < 8; ++j) {
    const int k = kk * 32 + ((l >> 4) * 8) + j;
    const float f = (k < Korig) ? W[k * HID + c * 16 + (l & 15)] : 0.0f;
    o.u[j] = f2bf(f);
  }
  reinterpret_cast<uint4*>(outb + (size_t)base_ks * 4096)[tid] = o.v;
}

// hs_proj = h @ mw1[0:128], hd_proj = h @ mw1[128:256]  (bf16 out)
__global__ __launch_bounds__(256, 3)
void proj_kernel(const float* __restrict__ h,
                 const ushort* __restrict__ wap, const ushort* __restrict__ wbp,
                 ushort* __restrict__ hs_proj, ushort* __restrict__ hd_proj)
{
  __shared__ __align__(16) ushort sH[64 * HID];   // 16 KB, swizzled
  char* const sHb = reinterpret_cast<char*>(sH);
  const int t  = threadIdx.x;
  const int n0 = blockIdx.x * 64;

  {  // build A tile (f32 -> bf16)
    const int e = t >> 2, c0 = (t & 3) * 32;
    const int node = n0 + e;
    const int sm = (e & 7) << 4;
    #pragma unroll
    for (int m = 0; m < 4; ++m) {
      const int c = c0 + m * 8;
      float4 f0 = make_float4(0,0,0,0), f1 = f0;
      if (node < NN) {
        f0 = *reinterpret_cast<const float4*>(h + (long)node * HID + c);
        f1 = *reinterpret_cast<const float4*>(h + (long)node * HID + c + 4);
      }
      union { ushort u[8]; uint4 v; } o;
      o.u[0]=f2bf(f0.x); o.u[1]=f2bf(f0.y); o.u[2]=f2bf(f0.z); o.u[3]=f2bf(f0.w);
      o.u[4]=f2bf(f1.x); o.u[5]=f2bf(f1.y); o.u[6]=f2bf(f1.z); o.u[7]=f2bf(f1.w);
      *reinterpret_cast<uint4*>(sHb + ((e * 256 + c * 2) ^ sm)) = o.v;
    }
  }
  __syncthreads();

  const int lane = t & 63;
  const int w    = t >> 6;
  const int rt0  = (w & 1) * 2;
  const int ct0  = (w >> 1) * 4;
  const int lrow = lane & 15;
  const int lk16 = (lane >> 4) * 16;
  const int rowA0 = rt0 * 16 + lrow, rowA1 = rowA0 + 16;
  const int smA0 = (rowA0 & 7) << 4, smA1 = (rowA1 & 7) << 4;

  floatx4 accA[2][4] = {}, accB[2][4] = {};
  const ushort* const baseA = wap + ((size_t)ct0 * 64 + lane) * 8;
  const ushort* const baseB = wbp + ((size_t)ct0 * 64 + lane) * 8;
  #pragma unroll
  for (int kk = 0; kk < 4; ++kk) {
    short8 afr[2];
    afr[0] = *reinterpret_cast<const short8*>(sHb + rowA0 * 256 + ((kk*64 + lk16) ^ smA0));
    afr[1] = *reinterpret_cast<const short8*>(sHb + rowA1 * 256 + ((kk*64 + lk16) ^ smA1));
    #pragma unroll
    for (int j = 0; j < 4; ++j) {
      const short8 bA = *reinterpret_cast<const short8*>(baseA + kk * 4096 + j * 512);
      const short8 bB = *reinterpret_cast<const short8*>(baseB + kk * 4096 + j * 512);
      #pragma unroll
      for (int i = 0; i < 2; ++i) {
        accA[i][j] = __builtin_amdgcn_mfma_f32_16x16x32_bf16(afr[i], bA, accA[i][j], 0, 0, 0);
        accB[i][j] = __builtin_amdgcn_mfma_f32_16x16x32_bf16(afr[i], bB, accB[i][j], 0, 0, 0);
      }
    }
  }
  #pragma unroll
  for (int i = 0; i < 2; ++i)
    #pragma unroll
    for (int r = 0; r < 4; ++r) {
      const int row = (rt0 + i) * 16 + (lane >> 4) * 4 + r;
      const int node = n0 + row;
      if (node < NN) {
        #pragma unroll
        for (int j = 0; j < 4; ++j) {
          const int col = (ct0 + j) * 16 + lrow;
          hs_proj[(long)node * HID + col] = f2bf(accA[i][j][r]);
          hd_proj[(long)node * HID + col] = f2bf(accB[i][j][r]);
        }
      }
    }
}

// 64 CSR-ordered edges/block (R12-proven). LDS: sBuf[0..16K) = PRE/X/MSG bf16
// (unioned, 256B swizzled rows); sBuf[16K..20K) = rbf frags. Layer-1 edge terms
// (rbf, dist, one-hot) via K=64 MFMA vs packed w1x.
// launch_bounds(256,4): 128-VGPR budget (R8 lesson: never cap below accumulators).
__global__ __launch_bounds__(256, 4)
void edge_kernel(const ushort* __restrict__ hs_proj, const ushort* __restrict__ hd_proj,
                 const float* __restrict__ pos, const int2* __restrict__ rec,
                 const ushort* __restrict__ w1xp, const ushort* __restrict__ w2p,
                 const float* __restrict__ mb2,
                 float* sums)
{
  __shared__ __align__(16) char sBuf[20480];
  __shared__ int   sDst[64];
  __shared__ int   sEt[64];
  __shared__ float sDistF[64];

  const int t  = threadIdx.x;
  const int e0 = blockIdx.x * 64;
  const int e  = t >> 2, q = t & 3;

  // phase0: edge record (coalesced, 4-lane redundant)
  const int2 rc = rec[e0 + e];
  const int src = rc.x & 0x00FFFFFF;
  const int et  = ((unsigned)rc.x) >> 24;
  const int dst = rc.y;

  const float dx = pos[3*src]   - pos[3*dst];
  const float dy = pos[3*src+1] - pos[3*dst+1];
  const float dz = pos[3*src+2] - pos[3*dst+2];
  const float dist = sqrtf(dx*dx + dy*dy + dz*dz);
  if (q == 0) { sDst[e] = dst; sEt[e] = et; sDistF[e] = dist; }

  // phase1: PRE = hs+hd (bf16, swizzled) + rbf frags
  {
    const ushort* const hsr = hs_proj + (long)src * HID;
    const ushort* const hdr = hd_proj + (long)dst * HID;
    const int sm = (e & 7) << 4;
    #pragma unroll
    for (int m = 0; m < 4; ++m) {
      const int c = q * 32 + m * 8;
      const uint4 a = *reinterpret_cast<const uint4*>(hsr + c);
      const uint4 b = *reinterpret_cast<const uint4*>(hdr + c);
      const ushort* au = reinterpret_cast<const ushort*>(&a);
      const ushort* bu = reinterpret_cast<const ushort*>(&b);
      union { ushort u[8]; uint4 v; } o;
      #pragma unroll
      for (int j = 0; j < 8; ++j) o.u[j] = f2bf(bf2f(au[j]) + bf2f(bu[j]));
      *reinterpret_cast<uint4*>(sBuf + ((e * 256 + c * 2) ^ sm)) = o.v;
    }
    const float step  = 6.0f / 31.0f;
    const float gamma = 1.0f / (step * step);
    const int r0 = q * 8;
    union { ushort u[8]; uint4 v; } o;
    #pragma unroll
    for (int j = 0; j < 8; ++j) {
      const float dd = dist - step * (float)(r0 + j);
      o.u[j] = f2bf(__expf(-gamma * dd * dd));
    }
    reinterpret_cast<uint4*>(sBuf + 16384)[e * 4 + (q ^ (e & 3))] = o.v;
  }
  __syncthreads();   // (1) PRE + rbf + sDst/sEt/sDistF visible

  const int lane = t & 63;
  const int w    = t >> 6;
  const int rt0  = (w & 1) * 2;
  const int ct0  = (w >> 1) * 4;
  const int lrow = lane & 15;
  const int lk16 = (lane >> 4) * 16;
  const int rowA0 = rt0 * 16 + lrow, rowA1 = rowA0 + 16;
  const int smA0 = (rowA0 & 7) << 4, smA1 = (rowA1 & 7) << 4;

  // layer 1: acc = PRE (C-layout bf16 reads) + [rbf | dist,onehot] @ w1x (K=64)
  floatx4 acc[2][4];
  #pragma unroll
  for (int i = 0; i < 2; ++i)
    #pragma unroll
    for (int r = 0; r < 4; ++r) {
      const int row = (rt0 + i) * 16 + (lane >> 4) * 4 + r;
      const int sm = (row & 7) << 4;
      #pragma unroll
      for (int j = 0; j < 4; ++j) {
        const int col = (ct0 + j) * 16 + lrow;
        acc[i][j][r] = bf2f(*reinterpret_cast<const ushort*>(
            sBuf + row * 256 + ((col * 2) ^ sm)));
      }
    }
  {
    const uint4* const sRbf = reinterpret_cast<const uint4*>(sBuf + 16384);
    const short8 a0 = *reinterpret_cast<const short8*>(&sRbf[rowA0 * 4 + ((lane >> 4) ^ (rowA0 & 3))]);
    const short8 a1 = *reinterpret_cast<const short8*>(&sRbf[rowA1 * 4 + ((lane >> 4) ^ (rowA1 & 3))]);
    const ushort* const bb = w1xp + ((size_t)ct0 * 64 + lane) * 8;
    #pragma unroll
    for (int j = 0; j < 4; ++j) {
      const short8 b = *reinterpret_cast<const short8*>(bb + j * 512);
      acc[0][j] = __builtin_amdgcn_mfma_f32_16x16x32_bf16(a0, b, acc[0][j], 0, 0, 0);
      acc[1][j] = __builtin_amdgcn_mfma_f32_16x16x32_bf16(a1, b, acc[1][j], 0, 0, 0);
    }
    short8 x0 = {0,0,0,0,0,0,0,0}, x1 = {0,0,0,0,0,0,0,0};
    if ((lane >> 4) == 0) {   // k = 32..39 slots: [dist, et==0, et==1, 0...]
      x0[0] = (short)f2bf(sDistF[rowA0]);
      x0[1] = (sEt[rowA0] == 0) ? (short)0x3F80 : (short)0;
      x0[2] = (sEt[rowA0] == 1) ? (short)0x3F80 : (short)0;
      x1[0] = (short)f2bf(sDistF[rowA1]);
      x1[1] = (sEt[rowA1] == 0) ? (short)0x3F80 : (short)0;
      x1[2] = (sEt[rowA1] == 1) ? (short)0x3F80 : (short)0;
    }
    #pragma unroll
    for (int j = 0; j < 4; ++j) {
      const short8 b = *reinterpret_cast<const short8*>(bb + 4096 + j * 512);
      acc[0][j] = __builtin_amdgcn_mfma_f32_16x16x32_bf16(x0, b, acc[0][j], 0, 0, 0);
      acc[1][j] = __builtin_amdgcn_mfma_f32_16x16x32_bf16(x1, b, acc[1][j], 0, 0, 0);
    }
  }

  // silu -> X (bf16). Each wave's X window == its own PRE-read window.
  #pragma unroll
  for (int i = 0; i < 2; ++i)
    #pragma unroll
    for (int r = 0; r < 4; ++r) {
      const int row = (rt0 + i) * 16 + (lane >> 4) * 4 + r;
      const int sm = (row & 7) << 4;
      #pragma unroll
      for (int j = 0; j < 4; ++j) {
        const int col = (ct0 + j) * 16 + lrow;
        *reinterpret_cast<ushort*>(sBuf + row * 256 + ((col * 2) ^ sm)) =
            f2bf(silu_f(acc[i][j][r]));
      }
    }
  __syncthreads();   // (3) X visible

  // layer 2: [64 x 128] @ [128 x 128]
  floatx4 acc2[2][4] = {};
  {
    const ushort* const bbase = w2p + ((size_t)ct0 * 64 + lane) * 8;
    #pragma unroll 2
    for (int kk = 0; kk < 4; ++kk) {
      short8 bfr[4];
      #pragma unroll
      for (int j = 0; j < 4; ++j)
        bfr[j] = *reinterpret_cast<const short8*>(bbase + kk * 4096 + j * 512);
      short8 afr[2];
      afr[0] = *reinterpret_cast<const short8*>(sBuf + rowA0 * 256 + ((kk*64 + lk16) ^ smA0));
      afr[1] = *reinterpret_cast<const short8*>(sBuf + rowA1 * 256 + ((kk*64 + lk16) ^ smA1));
      #pragma unroll
      for (int i = 0; i < 2; ++i)
        #pragma unroll
        for (int j = 0; j < 4; ++j)
          acc2[i][j] = __builtin_amdgcn_mfma_f32_16x16x32_bf16(afr[i], bfr[j], acc2[i][j], 0, 0, 0);
    }
  }
  __syncthreads();   // (4) all X reads done; region reusable

  // epilogue: bias + silu -> MSG (bf16, own window)
  {
    float b2v[4];
    #pragma unroll
    for (int j = 0; j < 4; ++j) b2v[j] = mb2[(ct0 + j) * 16 + lrow];
    #pragma unroll
    for (int i = 0; i < 2; ++i)
      #pragma unroll
      for (int r = 0; r < 4; ++r) {
        const int row = (rt0 + i) * 16 + (lane >> 4) * 4 + r;
        const int sm = (row & 7) << 4;
        #pragma unroll
        for (int j = 0; j < 4; ++j) {
          const int col = (ct0 + j) * 16 + lrow;
          *reinterpret_cast<ushort*>(sBuf + row * 256 + ((col * 2) ^ sm)) =
              f2bf(silu_f(acc2[i][j][r] + b2v[j]));
        }
      }
  }
  __syncthreads();   // (5) MSG visible

  // dst-segment reduction: one atomicAdd per (segment, column)
  {
    const int half = t >> 7;
    const int c    = t & 127;
    const int r0   = half * 32;
    int cur = sDst[r0];
    float accv = 0.0f;
    for (int r = r0; r < r0 + 32; ++r) {
      const int d = sDst[r];
      const float mv = bf2f(*reinterpret_cast<const ushort*>(
          sBuf + r * 256 + ((c * 2) ^ ((r & 7) << 4))));
      if (d != cur) {
        atomicAdd(&sums[(long)cur * HID + c], accv);
        accv = 0.0f;
        cur = d;
      }
      accv += mv;
    }
    atomicAdd(&sums[(long)cur * HID + c], accv);
  }
}

// f32-VALU node kernel with bf16 LDS staging (R12-proven).
// counts_f now holds 1/max(count,1) -> multiply instead of divide.
// sums aliases out (d_out) — no __restrict__ on either.
__global__ __launch_bounds__(256, 4)
void node_kernel(const float* __restrict__ h,
                 const float* sums, const float* __restrict__ counts_r,
                 const int* __restrict__ node_type,
                 const float* __restrict__ uw1, const float* __restrict__ ub1,
                 const float* __restrict__ uw2, const float* __restrict__ ub2,
                 const float* __restrict__ ln_g, const float* __restrict__ ln_b,
                 float* out)
{
  __shared__ ushort sIn[TILE_N * 256];   // 32 KB bf16

  const int t  = threadIdx.x;
  const int n0 = blockIdx.x * TILE_N;

  for (int idx = t; idx < TILE_N*HID; idx += 256) {
    const int n = idx >> 7, c = idx & (HID-1);
    const int node = n0 + n;
    float hv = 0.f, av = 0.f;
    if (node < NN) {
      hv = h[(long)node*HID + c];
      av = sums[(long)node*HID + c] * counts_r[node];
    }
    sIn[n*256 + c]       = f2bf(hv);
    sIn[n*256 + HID + c] = f2bf(av);
  }
  __syncthreads();   // (B0)

  const int tx = t & 31;
  const int ty = t >> 5;

  // GEMM1: [64 x 256] @ [256 x 128], f32 FMA with bf16 A
  const float* wp = uw1 + tx*4;
  float4 acc[8];
  #pragma unroll
  for (int i = 0; i < 8; ++i) acc[i] = make_float4(0.f,0.f,0.f,0.f);
  for (int k = 0; k < 2*HID; ++k) {
    const float4 w = *reinterpret_cast<const float4*>(wp + (long)k*HID);
    #pragma unroll
    for (int i = 0; i < 8; ++i) {
      const float a = bf2f(sIn[(ty*8+i)*256 + k]);
      acc[i].x = fmaf(a, w.x, acc[i].x);
      acc[i].y = fmaf(a, w.y, acc[i].y);
      acc[i].z = fmaf(a, w.z, acc[i].z);
      acc[i].w = fmaf(a, w.w, acc[i].w);
    }
  }
  __syncthreads();   // (B1)

  const float4 b1 = *reinterpret_cast<const float4*>(ub1 + tx*4);
  #pragma unroll
  for (int i = 0; i < 8; ++i) {
    const int e = ty*8 + i;
    float4 v = acc[i];
    ushort4 s;
    s.x = f2bf(silu_f(v.x + b1.x)); s.y = f2bf(silu_f(v.y + b1.y));
    s.z = f2bf(silu_f(v.z + b1.z)); s.w = f2bf(silu_f(v.w + b1.w));
    *reinterpret_cast<ushort4*>(&sIn[e*256 + tx*4]) = s;   // sU in h-half
  }
  __syncthreads();   // (B2)

  // GEMM2: [64 x 128] @ [128 x 128]
  const float* wp2 = uw2 + tx*4;
  float4 acc2[8];
  #pragma unroll
  for (int i = 0; i < 8; ++i) acc2[i] = make_float4(0.f,0.f,0.f,0.f);
  for (int k = 0; k < HID; ++k) {
    const float4 w = *reinterpret_cast<const float4*>(wp2 + (long)k*HID);
    #pragma unroll
    for (int i = 0; i < 8; ++i) {
      const float a = bf2f(sIn[(ty*8+i)*256 + k]);
      acc2[i].x = fmaf(a, w.x, acc2[i].x);
      acc2[i].y = fmaf(a, w.y, acc2[i].y);
      acc2[i].z = fmaf(a, w.z, acc2[i].z);
      acc2[i].w = fmaf(a, w.w, acc2[i].w);
    }
  }
  const float4 b2 = *reinterpret_cast<const float4*>(ub2 + tx*4);
  #pragma unroll
  for (int i = 0; i < 8; ++i) {
    const int e = ty*8 + i;
    ushort4 s;
    s.x = f2bf(acc2[i].x + b2.x); s.y = f2bf(acc2[i].y + b2.y);
    s.z = f2bf(acc2[i].z + b2.z); s.w = f2bf(acc2[i].w + b2.w);
    *reinterpret_cast<ushort4*>(&sIn[e*256 + HID + tx*4]) = s;   // u in agg-half
  }
  __syncthreads();   // (B3)

  {  // LayerNorm + residual + mask; x = h(f32) + u(bf16)
    const int n = t >> 2, q = t & 3;
    const int node = n0 + n;
    if (node < NN) {
      float4 hv4[8], xv4[8];
      float smm = 0.f, sqq = 0.f;
      #pragma unroll
      for (int m = 0; m < 8; ++m) {
        const int c = q * 32 + m * 4;
        const ushort4 us = *reinterpret_cast<const ushort4*>(&sIn[n*256 + HID + c]);
        const float4 hv = *reinterpret_cast<const float4*>(h + (long)node * HID + c);
        float4 x;
        x.x = hv.x + bf2f(us.x); x.y = hv.y + bf2f(us.y);
        x.z = hv.z + bf2f(us.z); x.w = hv.w + bf2f(us.w);
        hv4[m] = hv; xv4[m] = x;
        smm += x.x + x.y + x.z + x.w;
        sqq += x.x*x.x + x.y*x.y + x.z*x.z + x.w*x.w;
      }
      smm += __shfl_xor(smm, 1); sqq += __shfl_xor(sqq, 1);
      smm += __shfl_xor(smm, 2); sqq += __shfl_xor(sqq, 2);
      const float mu = smm * (1.0f / HID);
      float var = sqq * (1.0f / HID) - mu * mu;
      var = fmaxf(var, 0.0f);
      const float rs = rsqrtf(var + 1e-5f);
      const bool lig = (node_type[node] == 0);
      #pragma unroll
      for (int m = 0; m < 8; ++m) {
        const int c = q * 32 + m * 4;
        const float4 g = *reinterpret_cast<const float4*>(ln_g + c);
        const float4 b = *reinterpret_cast<const float4*>(ln_b + c);
        float4 o;
        o.x = lig ? (xv4[m].x - mu) * rs * g.x + b.x : hv4[m].x;
        o.y = lig ? (xv4[m].y - mu) * rs * g.y + b.y : hv4[m].y;
        o.z = lig ? (xv4[m].z - mu) * rs * g.z + b.z : hv4[m].z;
        o.w = lig ? (xv4[m].w - mu) * rs * g.w + b.w : hv4[m].w;
        *reinterpret_cast<float4*>(out + (long)node * HID + c) = o;
      }
    }
  }
}

extern "C" void kernel_launch(void* const* d_in, const int* in_sizes, int n_in,
                              void* d_out, int out_size, void* d_ws, size_t ws_size,
                              hipStream_t stream)
{
  const float* h    = (const float*)d_in[0];
  const float* pos  = (const float*)d_in[1];
  const int*   eidx = (const int*)  d_in[2];
  const int*   etyp = (const int*)  d_in[3];
  const int*   ntyp = (const int*)  d_in[4];
  const float* emb  = (const float*)d_in[5];
  const float* mw1  = (const float*)d_in[6];
  const float* mb1  = (const float*)d_in[7];
  const float* mw2  = (const float*)d_in[8];
  const float* mb2  = (const float*)d_in[9];
  const float* uw1  = (const float*)d_in[10];
  const float* ub1  = (const float*)d_in[11];
  const float* uw2  = (const float*)d_in[12];
  const float* ub2  = (const float*)d_in[13];
  const float* lng  = (const float*)d_in[14];
  const float* lnb  = (const float*)d_in[15];

  // f32 sums accumulate in d_out (exactly NN*HID f32); node_kernel reads a
  // node's sums strictly before writing the same node's output row.
  float* sums = (float*)d_out;

  // workspace layout (~33 MB)
  float*  counts_r = (float*)d_ws;                      // NN f32 (reciprocal)
  ushort* hs_proj  = (ushort*)(counts_r + NN);          // NN*HID bf16
  ushort* hd_proj  = hs_proj + (long)NN*HID;            // NN*HID bf16
  float*  embp     = (float*)(hd_proj + (long)NN*HID);  // 256 f32
  float*  w1x      = embp + 256;                        // 64*128 f32
  ushort* packs    = (ushort*)(w1x + 64*128);           // 14 ksteps contiguous
  ushort* wap      = packs;                             // 4 ks
  ushort* wbp      = wap  + 4*4096;                     // 4 ks
  ushort* w1xp     = wbp  + 4*4096;                     // 2 ks
  ushort* w2p      = w1xp + 2*4096;                     // 4 ks
  int*    cnt_i    = (int*)(w2p + 4*4096);              // NN
  int*    cursor   = cnt_i + NN;                        // NN (adjacent: one memset)
  int*    starts   = cursor + NN;                       // NN
  int*    bsum     = starts + NN;                       // 256
  int2*   rec      = (int2*)(bsum + 256);               // NE * 8B

  hipMemsetAsync(sums, 0, (size_t)NN*HID*4, stream);
  hipMemsetAsync(cnt_i, 0, (size_t)NN*2*4, stream);     // cnt_i + cursor

  // CSR build
  counts_i_kernel<<<(NE + 255)/256, 256, 0, stream>>>(eidx, cnt_i);
  scan_a_kernel<<<NSCAN_BLOCKS, 256, 0, stream>>>(cnt_i, starts, bsum);
  scan_b_kernel<<<1, 256, 0, stream>>>(bsum, NSCAN_BLOCKS);
  scan_c_kernel<<<NSCAN_BLOCKS, 256, 0, stream>>>(starts, cnt_i, bsum, counts_r);
  perm_kernel<<<(NE + 255)/256, 256, 0, stream>>>(eidx, etyp, starts, cursor, rec);

  // weight prep: fused embp+w1x, then fused 4-matrix pack
  prep_kernel<<<1, 256, 0, stream>>>(emb, mw1, mb1, embp, w1x);
  pack4_kernel<<<28, 256, 0, stream>>>(mw1, w1x, mw2, packs);

  proj_kernel<<<(NN + 63)/64, 256, 0, stream>>>(h, wap, wbp, hs_proj, hd_proj);
  edge_kernel<<<NE/64, 256, 0, stream>>>(hs_proj, hd_proj, pos, rec,
                                         w1xp, w2p, mb2, sums);
  node_kernel<<<(NN + 63)/64, 256, 0, stream>>>(h, sums, counts_r, ntyp,
                                                uw1, ub1, uw2, ub2,
                                                lng, lnb, (float*)d_out);
}